// Round 2
// baseline (843.866 us; speedup 1.0000x reference)
//
#include <hip/hip_runtime.h>

#define T_DIM 8192
#define H_DIM 1024
#define E_NUM 64
#define I_DIM 512
#define K_TOP 6
#define CAP   1536
#define SCALE 2.5f

typedef __attribute__((ext_vector_type(8))) short short8;
typedef __attribute__((ext_vector_type(4))) float floatx4;

__device__ __forceinline__ unsigned short f2bf(float f) {
    unsigned u = __float_as_uint(f);
    u += 0x7FFF + ((u >> 16) & 1);          // round-to-nearest-even
    return (unsigned short)(u >> 16);
}
__device__ __forceinline__ float bf2f(unsigned short h) {
    return __uint_as_float(((unsigned)h) << 16);
}

// async global->LDS, 16 B per lane (wave-uniform LDS base + lane*16)
__device__ __forceinline__ void gload_lds16(const void* g, void* l) {
    __builtin_amdgcn_global_load_lds(
        (const __attribute__((address_space(1))) unsigned int*)g,
        (__attribute__((address_space(3))) unsigned int*)l, 16, 0, 0);
}

// ---------------------------------------------------------------------------
// 1) Router logits (fp32 exact): 1024 waves x 8 tokens, scalar x loads,
//    coalesced gw column loads.  logits[T,64] = x[T,1024] @ gw[1024,64]
// ---------------------------------------------------------------------------
__global__ __launch_bounds__(256) void router_logits_kernel(
    const float* __restrict__ x, const float* __restrict__ gw,
    float* __restrict__ logits) {
    const int wave = blockIdx.x * 4 + (threadIdx.x >> 6);   // 0..1023
    const int lane = threadIdx.x & 63;                      // expert id
    const int t0 = __builtin_amdgcn_readfirstlane(wave * 8);
    float acc[8] = {0.f, 0.f, 0.f, 0.f, 0.f, 0.f, 0.f, 0.f};
    for (int h0 = 0; h0 < H_DIM; h0 += 4) {
        float4 xv[8];
#pragma unroll
        for (int tt = 0; tt < 8; tt++)
            xv[tt] = *(const float4*)(x + (size_t)(t0 + tt) * H_DIM + h0);
#pragma unroll
        for (int j = 0; j < 4; j++) {
            float wv = gw[(size_t)(h0 + j) * E_NUM + lane];
#pragma unroll
            for (int tt = 0; tt < 8; tt++)
                acc[tt] += (&xv[tt].x)[j] * wv;
        }
    }
#pragma unroll
    for (int tt = 0; tt < 8; tt++)
        logits[(size_t)(t0 + tt) * E_NUM + lane] = acc[tt];
}

// ---------------------------------------------------------------------------
// 2) Grouped sigmoid top-k routing + atomic dispatch.  One thread per token.
// ---------------------------------------------------------------------------
__global__ __launch_bounds__(64) void route_kernel(
    const float* __restrict__ logits, const float* __restrict__ bias,
    int* __restrict__ ids, float* __restrict__ wts, int* __restrict__ poss,
    int* __restrict__ cnt, int* __restrict__ tlist) {
    __shared__ float sc[64][65];
    const int tid = threadIdx.x;
    const int t = blockIdx.x * 64 + tid;
    const float* lrow = logits + (size_t)t * E_NUM;

#pragma unroll
    for (int e = 0; e < 64; e++) {
        float s = 1.0f / (1.0f + expf(-lrow[e]));
        sc[e][tid] = s + bias[e];
    }
    float gs[8];
#pragma unroll
    for (int g = 0; g < 8; g++) {
        float m1 = -1e30f, m2 = -1e30f;
#pragma unroll
        for (int i = 0; i < 8; i++) {
            float v = sc[g * 8 + i][tid];
            if (v > m1) { m2 = m1; m1 = v; } else if (v > m2) { m2 = v; }
        }
        gs[g] = m1 + m2;
    }
    unsigned gm = 0;
    for (int k = 0; k < 4; k++) {
        float best = -1e30f; int bi = 0;
#pragma unroll
        for (int g = 0; g < 8; g++) {
            bool ok = !((gm >> g) & 1);
            if (ok && gs[g] > best) { best = gs[g]; bi = g; }
        }
        gm |= 1u << bi;
    }
    unsigned long long taken = 0;
    int   idk[K_TOP];
    float wk[K_TOP];
    float wsum = 0.f;
    for (int k = 0; k < K_TOP; k++) {
        float best = -1e30f; int bi = 0;
#pragma unroll
        for (int e = 0; e < 64; e++) {
            bool allow = ((gm >> (e >> 3)) & 1) && !((taken >> e) & 1);
            float v = sc[e][tid];
            if (allow && v > best) { best = v; bi = e; }
        }
        taken |= 1ull << bi;
        idk[k] = bi;
        float s = 1.0f / (1.0f + expf(-lrow[bi]));
        wk[k] = s; wsum += s;
    }
    float inv = 1.0f / wsum;
#pragma unroll
    for (int k = 0; k < K_TOP; k++) {
        int e = idk[k];
        ids[(size_t)t * K_TOP + k] = e;
        wts[(size_t)t * K_TOP + k] = wk[k] * inv;
        int p = atomicAdd(&cnt[e], 1);
        if (p < CAP) { tlist[e * CAP + p] = t; poss[(size_t)t * K_TOP + k] = p; }
        else         { poss[(size_t)t * K_TOP + k] = -1; }
    }
}

// ---------------------------------------------------------------------------
// 3) Exclusive scan of per-expert counts -> packed row bases
// ---------------------------------------------------------------------------
__global__ void scan_kernel(const int* __restrict__ cnt, int* __restrict__ base) {
    if (threadIdx.x == 0 && blockIdx.x == 0) {
        int s = 0;
        for (int e = 0; e < E_NUM; e++) {
            base[e] = s;
            int c = cnt[e]; if (c > CAP) c = CAP;
            s += c;
        }
    }
}

// ---------------------------------------------------------------------------
// 4) x fp32 -> bf16
// ---------------------------------------------------------------------------
__global__ __launch_bounds__(256) void cvt_x_kernel(
    const float* __restrict__ x, unsigned short* __restrict__ xb) {
    size_t i = ((size_t)blockIdx.x * 256 + threadIdx.x) * 4;
    float4 v = *(const float4*)(x + i);
    ushort4 o;
    o.x = f2bf(v.x); o.y = f2bf(v.y); o.z = f2bf(v.z); o.w = f2bf(v.w);
    *(ushort4*)(xb + i) = o;
}

// ---------------------------------------------------------------------------
// 5) Batched transpose + convert: src [B][R][C] fp32 -> dst [B][C][R] bf16
// ---------------------------------------------------------------------------
__global__ __launch_bounds__(256) void transpose_kernel(
    const float* __restrict__ src, unsigned short* __restrict__ dst, int R, int C) {
    const int b = blockIdx.z;
    src += (size_t)b * R * C;
    dst += (size_t)b * R * C;
    const int r0 = blockIdx.y * 64, c0 = blockIdx.x * 64;
    __shared__ unsigned short tbuf[64][68];
    const int tid = threadIdx.x;
    const int rr = tid >> 4, c4 = (tid & 15) * 4;
#pragma unroll
    for (int i = 0; i < 4; i++) {
        int r = rr + i * 16;
        float4 v = *(const float4*)(src + (size_t)(r0 + r) * C + c0 + c4);
        tbuf[r][c4 + 0] = f2bf(v.x); tbuf[r][c4 + 1] = f2bf(v.y);
        tbuf[r][c4 + 2] = f2bf(v.z); tbuf[r][c4 + 3] = f2bf(v.w);
    }
    __syncthreads();
#pragma unroll
    for (int i = 0; i < 4; i++) {
        int ci = rr + i * 16;
        ushort4 o;
        o.x = tbuf[c4 + 0][ci]; o.y = tbuf[c4 + 1][ci];
        o.z = tbuf[c4 + 2][ci]; o.w = tbuf[c4 + 3][ci];
        *(ushort4*)(dst + (size_t)(c0 + ci) * R + r0 + c4) = o;
    }
}

// ---------------------------------------------------------------------------
// 6) MFMA GEMM, 128x128 tile, BK=64, global_load_lds(16B) staging into
//    unpadded LDS with XOR k-chunk swizzle (conflict-free ds_read_b128).
//    A [M,K] bf16 (opt. gathered rows), B [N,K] bf16 (pre-transposed),
//    C row-major [.,N]: bf16 (+opt relu^2) or fp32.
// ---------------------------------------------------------------------------
template <bool GATHER, bool RELU2, bool OUTF32>
__global__ __launch_bounds__(256, 2) void gemm_kernel(
    const unsigned short* __restrict__ A, const unsigned short* __restrict__ B,
    void* __restrict__ Cout,
    const int* __restrict__ cnt, const int* __restrict__ basep,
    const int* __restrict__ tlist,
    int N, int K, int fixedM) {
    const int e = blockIdx.z;
    const int M = cnt ? min(cnt[e], CAP) : fixedM;
    const int m0 = blockIdx.y * 128;
    if (m0 >= M) return;
    const int n0 = blockIdx.x * 128;
    const int rowbase = basep ? basep[e] : 0;
    const unsigned short* Be = B + (size_t)e * (size_t)N * K;

    __shared__ __align__(16) unsigned short a_s[128 * 64];
    __shared__ __align__(16) unsigned short b_s[128 * 64];

    const int tid  = threadIdx.x;
    const int w    = tid >> 6;
    const int lane = tid & 63;
    const int rsub = lane >> 3;             // 0..7 row within 8-row chunk
    const int csw  = (lane & 7) ^ rsub;     // swizzled k-chunk this lane fetches

    // per-lane global row pointers for the 4 staging instructions each of A/B
    const unsigned short* aptr[4];
    const unsigned short* bptr[4];
#pragma unroll
    for (int j = 0; j < 4; j++) {
        int r = m0 + w * 32 + j * 8 + rsub;
        if (GATHER) {
            int t = (r < M) ? tlist[e * CAP + r] : 0;   // clamp: garbage rows masked at store
            aptr[j] = A + (size_t)t * K + csw * 8;
        } else {
            int rr = (r < M) ? r : (M - 1);
            aptr[j] = A + (size_t)(rowbase + rr) * K + csw * 8;
        }
        bptr[j] = Be + (size_t)(n0 + w * 32 + j * 8 + rsub) * K + csw * 8;
    }

    const int wm = (w >> 1) * 64, wn = (w & 1) * 64;
    const int lm = lane & 15, q = lane >> 4;
    const int swm = lm & 7;                 // row&7 for fragment rows

    floatx4 acc[4][4];
#pragma unroll
    for (int a = 0; a < 4; a++)
#pragma unroll
        for (int b2 = 0; b2 < 4; b2++) acc[a][b2] = (floatx4){0.f, 0.f, 0.f, 0.f};

    for (int k0 = 0; k0 < K; k0 += 64) {
#pragma unroll
        for (int j = 0; j < 4; j++) {
            gload_lds16(aptr[j] + k0, &a_s[(w * 32 + j * 8) * 64]);
            gload_lds16(bptr[j] + k0, &b_s[(w * 32 + j * 8) * 64]);
        }
        __syncthreads();   // drains vmcnt (global_load_lds) before reads
#pragma unroll
        for (int kk = 0; kk < 2; kk++) {
            short8 af[4], bfr[4];
            const int ca = ((kk * 4 + q) ^ swm) * 8;
#pragma unroll
            for (int i = 0; i < 4; i++) {
                af[i]  = *(const short8*)&a_s[(wm + i * 16 + lm) * 64 + ca];
                bfr[i] = *(const short8*)&b_s[(wn + i * 16 + lm) * 64 + ca];
            }
#pragma unroll
            for (int mi = 0; mi < 4; mi++)
#pragma unroll
                for (int ni = 0; ni < 4; ni++)
                    acc[mi][ni] = __builtin_amdgcn_mfma_f32_16x16x32_bf16(
                        af[mi], bfr[ni], acc[mi][ni], 0, 0, 0);
        }
        __syncthreads();
    }

    // ---- epilogue ----
#pragma unroll
    for (int mi = 0; mi < 4; mi++) {
#pragma unroll
        for (int i = 0; i < 4; i++) {
            int r = wm + mi * 16 + q * 4 + i;
            if (m0 + r < M) {
                size_t Rrow = (size_t)(rowbase + m0 + r);
#pragma unroll
                for (int ni = 0; ni < 4; ni++) {
                    float v = acc[mi][ni][i];
                    if (RELU2) { v = v > 0.f ? v * v : 0.f; }
                    int c = n0 + wn + ni * 16 + lm;
                    if (OUTF32) ((float*)Cout)[Rrow * N + c] = v;
                    else        ((unsigned short*)Cout)[Rrow * N + c] = f2bf(v);
                }
            }
        }
    }
}

// ---------------------------------------------------------------------------
// 7) Combine: out[t] += SCALE * sum_k w[t,k] * Y[base[id]+pos]
// ---------------------------------------------------------------------------
__global__ __launch_bounds__(256) void combine_kernel(
    const unsigned short* __restrict__ Y, const int* __restrict__ ids,
    const float* __restrict__ wts, const int* __restrict__ poss,
    const int* __restrict__ base, float* __restrict__ out) {
    __shared__ int   s_slot[K_TOP];
    __shared__ float s_w[K_TOP];
    const int t = blockIdx.x, tid = threadIdx.x;
    if (tid < K_TOP) {
        int id = ids[(size_t)t * K_TOP + tid];
        int p  = poss[(size_t)t * K_TOP + tid];
        s_slot[tid] = (p >= 0) ? (base[id] + p) : -1;
        s_w[tid]    = wts[(size_t)t * K_TOP + tid];
    }
    __syncthreads();
    const int c = tid * 4;
    float a0 = 0.f, a1 = 0.f, a2 = 0.f, a3 = 0.f;
#pragma unroll
    for (int k = 0; k < K_TOP; k++) {
        int slot = s_slot[k];
        if (slot >= 0) {
            float wkk = s_w[k];
            ushort4 y = *(const ushort4*)(Y + (size_t)slot * H_DIM + c);
            a0 += wkk * bf2f(y.x); a1 += wkk * bf2f(y.y);
            a2 += wkk * bf2f(y.z); a3 += wkk * bf2f(y.w);
        }
    }
    float4 o = *(float4*)(out + (size_t)t * H_DIM + c);
    o.x += SCALE * a0; o.y += SCALE * a1; o.z += SCALE * a2; o.w += SCALE * a3;
    *(float4*)(out + (size_t)t * H_DIM + c) = o;
}

// ---------------------------------------------------------------------------
extern "C" void kernel_launch(void* const* d_in, const int* in_sizes, int n_in,
                              void* d_out, int out_size, void* d_ws, size_t ws_size,
                              hipStream_t stream) {
    const float* x         = (const float*)d_in[0];
    const float* gate_w    = (const float*)d_in[1];
    const float* gate_bias = (const float*)d_in[2];
    const float* w_up      = (const float*)d_in[3];
    const float* w_down    = (const float*)d_in[4];
    const float* sh_up     = (const float*)d_in[5];
    const float* sh_down   = (const float*)d_in[6];
    float* out = (float*)d_out;

    char* ws = (char*)d_ws;
    size_t off = 0;
    auto alloc = [&](size_t b) { size_t o = off; off += (b + 255) & ~(size_t)255; return o; };
    float*          logits = (float*)(ws + alloc((size_t)T_DIM * E_NUM * 4));
    int*            ids    = (int*)  (ws + alloc((size_t)T_DIM * K_TOP * 4));
    float*          wts    = (float*)(ws + alloc((size_t)T_DIM * K_TOP * 4));
    int*            poss   = (int*)  (ws + alloc((size_t)T_DIM * K_TOP * 4));
    int*            cnt    = (int*)  (ws + alloc(256));
    int*            base   = (int*)  (ws + alloc(256));
    int*            tlist  = (int*)  (ws + alloc((size_t)E_NUM * CAP * 4));
    unsigned short* xb     = (unsigned short*)(ws + alloc((size_t)T_DIM * H_DIM * 2));
    unsigned short* wupT   = (unsigned short*)(ws + alloc((size_t)E_NUM * H_DIM * I_DIM * 2));
    unsigned short* wdnT   = (unsigned short*)(ws + alloc((size_t)E_NUM * H_DIM * I_DIM * 2));
    unsigned short* shupT  = (unsigned short*)(ws + alloc((size_t)H_DIM * H_DIM * 2));
    unsigned short* shdnT  = (unsigned short*)(ws + alloc((size_t)H_DIM * H_DIM * 2));
    unsigned short* hact   = (unsigned short*)(ws + alloc((size_t)T_DIM * K_TOP * I_DIM * 2));
    unsigned short* Ybuf   = (unsigned short*)(ws + alloc((size_t)T_DIM * K_TOP * H_DIM * 2));
    unsigned short* smid   = (unsigned short*)(ws + alloc((size_t)T_DIM * H_DIM * 2));

    hipMemsetAsync(cnt, 0, 256, stream);

    router_logits_kernel<<<dim3(T_DIM / 32), 256, 0, stream>>>(x, gate_w, logits);
    route_kernel<<<dim3(T_DIM / 64), 64, 0, stream>>>(logits, gate_bias, ids, wts, poss, cnt, tlist);
    scan_kernel<<<1, 64, 0, stream>>>(cnt, base);
    cvt_x_kernel<<<dim3((T_DIM * H_DIM / 4) / 256), 256, 0, stream>>>(x, xb);
    transpose_kernel<<<dim3(I_DIM / 64, H_DIM / 64, E_NUM), 256, 0, stream>>>(w_up, wupT, H_DIM, I_DIM);
    transpose_kernel<<<dim3(H_DIM / 64, I_DIM / 64, E_NUM), 256, 0, stream>>>(w_down, wdnT, I_DIM, H_DIM);
    transpose_kernel<<<dim3(H_DIM / 64, H_DIM / 64, 1), 256, 0, stream>>>(sh_up, shupT, H_DIM, H_DIM);
    transpose_kernel<<<dim3(H_DIM / 64, H_DIM / 64, 1), 256, 0, stream>>>(sh_down, shdnT, H_DIM, H_DIM);

    gemm_kernel<true, true, false><<<dim3(I_DIM / 128, CAP / 128, E_NUM), 256, 0, stream>>>(
        xb, wupT, hact, cnt, base, tlist, I_DIM, H_DIM, 0);
    gemm_kernel<false, false, false><<<dim3(H_DIM / 128, CAP / 128, E_NUM), 256, 0, stream>>>(
        hact, wdnT, Ybuf, cnt, base, nullptr, H_DIM, I_DIM, 0);
    gemm_kernel<false, true, false><<<dim3(H_DIM / 128, T_DIM / 128, 1), 256, 0, stream>>>(
        xb, shupT, smid, nullptr, nullptr, nullptr, H_DIM, H_DIM, T_DIM);
    gemm_kernel<false, false, true><<<dim3(H_DIM / 128, T_DIM / 128, 1), 256, 0, stream>>>(
        smid, shdnT, out, nullptr, nullptr, nullptr, H_DIM, H_DIM, T_DIM);
    combine_kernel<<<dim3(T_DIM), 256, 0, stream>>>(Ybuf, ids, wts, poss, base, out);
    (void)in_sizes; (void)n_in; (void)out_size; (void)ws_size;
}

// Round 3
// 731.250 us; speedup vs baseline: 1.1540x; 1.1540x over previous
//
#include <hip/hip_runtime.h>

#define T_DIM 8192
#define H_DIM 1024
#define E_NUM 64
#define I_DIM 512
#define K_TOP 6
#define CAP   1536
#define SCALE 2.5f

typedef __attribute__((ext_vector_type(8))) short short8;
typedef __attribute__((ext_vector_type(4))) float floatx4;

__device__ __forceinline__ unsigned short f2bf(float f) {
    unsigned u = __float_as_uint(f);
    u += 0x7FFF + ((u >> 16) & 1);          // round-to-nearest-even
    return (unsigned short)(u >> 16);
}
__device__ __forceinline__ float bf2f(unsigned short h) {
    return __uint_as_float(((unsigned)h) << 16);
}

// async global->LDS, 16 B per lane (wave-uniform LDS base + lane*16)
__device__ __forceinline__ void gload_lds16(const void* g, void* l) {
    __builtin_amdgcn_global_load_lds(
        (const __attribute__((address_space(1))) unsigned int*)g,
        (__attribute__((address_space(3))) unsigned int*)l, 16, 0, 0);
}

// ---------------------------------------------------------------------------
// 1a) Router partial logits (fp32): 64-token x 64-expert LDS tile, 4x4 regs.
//     Split-K over H: blockIdx.y picks a 256-wide H segment -> part[seg].
//     Grid 128x4 = 512 blocks (2/CU, 8 waves/CU) fixes R2's occupancy hole.
// ---------------------------------------------------------------------------
__global__ __launch_bounds__(256) void router_partial_kernel(
    const float* __restrict__ x, const float* __restrict__ gw,
    float* __restrict__ part) {
    __shared__ float xs[64][68];
    __shared__ float wsh[64][68];
    const int t0   = blockIdx.x * 64;
    const int hbeg = blockIdx.y * 256;
    const int tid  = threadIdx.x;
    const int rr   = tid >> 4;           // 0..15
    const int c4   = (tid & 15) * 4;     // 0..60
    const int ty   = tid >> 4, tx = tid & 15;

    float acc[4][4];
#pragma unroll
    for (int j = 0; j < 4; j++)
#pragma unroll
        for (int l = 0; l < 4; l++) acc[j][l] = 0.f;

    for (int h0 = hbeg; h0 < hbeg + 256; h0 += 64) {
#pragma unroll
        for (int i = 0; i < 4; i++) {
            int r = rr + i * 16;
            float4 v = *(const float4*)(x + (size_t)(t0 + r) * H_DIM + h0 + c4);
            xs[r][c4 + 0] = v.x; xs[r][c4 + 1] = v.y; xs[r][c4 + 2] = v.z; xs[r][c4 + 3] = v.w;
            float4 w = *(const float4*)(gw + (size_t)(h0 + r) * E_NUM + c4);
            wsh[r][c4 + 0] = w.x; wsh[r][c4 + 1] = w.y; wsh[r][c4 + 2] = w.z; wsh[r][c4 + 3] = w.w;
        }
        __syncthreads();
#pragma unroll 8
        for (int kh = 0; kh < 64; kh++) {
            float a0 = xs[ty * 4 + 0][kh], a1 = xs[ty * 4 + 1][kh];
            float a2 = xs[ty * 4 + 2][kh], a3 = xs[ty * 4 + 3][kh];
            float b0 = wsh[kh][tx * 4 + 0], b1 = wsh[kh][tx * 4 + 1];
            float b2 = wsh[kh][tx * 4 + 2], b3 = wsh[kh][tx * 4 + 3];
            acc[0][0] += a0 * b0; acc[0][1] += a0 * b1; acc[0][2] += a0 * b2; acc[0][3] += a0 * b3;
            acc[1][0] += a1 * b0; acc[1][1] += a1 * b1; acc[1][2] += a1 * b2; acc[1][3] += a1 * b3;
            acc[2][0] += a2 * b0; acc[2][1] += a2 * b1; acc[2][2] += a2 * b2; acc[2][3] += a2 * b3;
            acc[3][0] += a3 * b0; acc[3][1] += a3 * b1; acc[3][2] += a3 * b2; acc[3][3] += a3 * b3;
        }
        __syncthreads();
    }
    float* dst = part + ((size_t)blockIdx.y * T_DIM + t0) * E_NUM;
#pragma unroll
    for (int j = 0; j < 4; j++)
#pragma unroll
        for (int l = 0; l < 4; l++)
            dst[(size_t)(ty * 4 + j) * E_NUM + tx * 4 + l] = acc[j][l];
}

// ---------------------------------------------------------------------------
// 1b) Reduce the 4 H-segment partials in FIXED order (deterministic fp32).
// ---------------------------------------------------------------------------
__global__ __launch_bounds__(256) void router_reduce_kernel(
    const float* __restrict__ part, float* __restrict__ logits) {
    const size_t S = (size_t)T_DIM * E_NUM;
    size_t i = ((size_t)blockIdx.x * 256 + threadIdx.x) * 4;
    float4 a = *(const float4*)(part + i);
    float4 b = *(const float4*)(part + S + i);
    float4 c = *(const float4*)(part + 2 * S + i);
    float4 d = *(const float4*)(part + 3 * S + i);
    float4 o;
    o.x = ((a.x + b.x) + c.x) + d.x;
    o.y = ((a.y + b.y) + c.y) + d.y;
    o.z = ((a.z + b.z) + c.z) + d.z;
    o.w = ((a.w + b.w) + c.w) + d.w;
    *(float4*)(logits + i) = o;
}

// ---------------------------------------------------------------------------
// 2) Grouped sigmoid top-k routing + atomic dispatch.  One thread per token.
// ---------------------------------------------------------------------------
__global__ __launch_bounds__(64) void route_kernel(
    const float* __restrict__ logits, const float* __restrict__ bias,
    int* __restrict__ ids, float* __restrict__ wts, int* __restrict__ poss,
    int* __restrict__ cnt, int* __restrict__ tlist) {
    __shared__ float sc[64][65];
    const int tid = threadIdx.x;
    const int t = blockIdx.x * 64 + tid;
    const float* lrow = logits + (size_t)t * E_NUM;

#pragma unroll
    for (int e = 0; e < 64; e++) {
        float s = 1.0f / (1.0f + expf(-lrow[e]));
        sc[e][tid] = s + bias[e];
    }
    float gs[8];
#pragma unroll
    for (int g = 0; g < 8; g++) {
        float m1 = -1e30f, m2 = -1e30f;
#pragma unroll
        for (int i = 0; i < 8; i++) {
            float v = sc[g * 8 + i][tid];
            if (v > m1) { m2 = m1; m1 = v; } else if (v > m2) { m2 = v; }
        }
        gs[g] = m1 + m2;
    }
    unsigned gm = 0;
    for (int k = 0; k < 4; k++) {
        float best = -1e30f; int bi = 0;
#pragma unroll
        for (int g = 0; g < 8; g++) {
            bool ok = !((gm >> g) & 1);
            if (ok && gs[g] > best) { best = gs[g]; bi = g; }
        }
        gm |= 1u << bi;
    }
    unsigned long long taken = 0;
    int   idk[K_TOP];
    float wk[K_TOP];
    float wsum = 0.f;
    for (int k = 0; k < K_TOP; k++) {
        float best = -1e30f; int bi = 0;
#pragma unroll
        for (int e = 0; e < 64; e++) {
            bool allow = ((gm >> (e >> 3)) & 1) && !((taken >> e) & 1);
            float v = sc[e][tid];
            if (allow && v > best) { best = v; bi = e; }
        }
        taken |= 1ull << bi;
        idk[k] = bi;
        float s = 1.0f / (1.0f + expf(-lrow[bi]));
        wk[k] = s; wsum += s;
    }
    float inv = 1.0f / wsum;
#pragma unroll
    for (int k = 0; k < K_TOP; k++) {
        int e = idk[k];
        ids[(size_t)t * K_TOP + k] = e;
        wts[(size_t)t * K_TOP + k] = wk[k] * inv;
        int p = atomicAdd(&cnt[e], 1);
        if (p < CAP) { tlist[e * CAP + p] = t; poss[(size_t)t * K_TOP + k] = p; }
        else         { poss[(size_t)t * K_TOP + k] = -1; }
    }
}

// ---------------------------------------------------------------------------
// 3) Exclusive scan of per-expert counts -> packed row bases
// ---------------------------------------------------------------------------
__global__ void scan_kernel(const int* __restrict__ cnt, int* __restrict__ base) {
    if (threadIdx.x == 0 && blockIdx.x == 0) {
        int s = 0;
        for (int e = 0; e < E_NUM; e++) {
            base[e] = s;
            int c = cnt[e]; if (c > CAP) c = CAP;
            s += c;
        }
    }
}

// ---------------------------------------------------------------------------
// 4) x fp32 -> bf16
// ---------------------------------------------------------------------------
__global__ __launch_bounds__(256) void cvt_x_kernel(
    const float* __restrict__ x, unsigned short* __restrict__ xb) {
    size_t i = ((size_t)blockIdx.x * 256 + threadIdx.x) * 4;
    float4 v = *(const float4*)(x + i);
    ushort4 o;
    o.x = f2bf(v.x); o.y = f2bf(v.y); o.z = f2bf(v.z); o.w = f2bf(v.w);
    *(ushort4*)(xb + i) = o;
}

// ---------------------------------------------------------------------------
// 5) Batched transpose + convert: src [B][R][C] fp32 -> dst [B][C][R] bf16
// ---------------------------------------------------------------------------
__global__ __launch_bounds__(256) void transpose_kernel(
    const float* __restrict__ src, unsigned short* __restrict__ dst, int R, int C) {
    const int b = blockIdx.z;
    src += (size_t)b * R * C;
    dst += (size_t)b * R * C;
    const int r0 = blockIdx.y * 64, c0 = blockIdx.x * 64;
    __shared__ unsigned short tbuf[64][68];
    const int tid = threadIdx.x;
    const int rr = tid >> 4, c4 = (tid & 15) * 4;
#pragma unroll
    for (int i = 0; i < 4; i++) {
        int r = rr + i * 16;
        float4 v = *(const float4*)(src + (size_t)(r0 + r) * C + c0 + c4);
        tbuf[r][c4 + 0] = f2bf(v.x); tbuf[r][c4 + 1] = f2bf(v.y);
        tbuf[r][c4 + 2] = f2bf(v.z); tbuf[r][c4 + 3] = f2bf(v.w);
    }
    __syncthreads();
#pragma unroll
    for (int i = 0; i < 4; i++) {
        int ci = rr + i * 16;
        ushort4 o;
        o.x = tbuf[c4 + 0][ci]; o.y = tbuf[c4 + 1][ci];
        o.z = tbuf[c4 + 2][ci]; o.w = tbuf[c4 + 3][ci];
        *(ushort4*)(dst + (size_t)(c0 + ci) * R + r0 + c4) = o;
    }
}

// ---------------------------------------------------------------------------
// 6) MFMA GEMM, 128x128 tile, BK=64, global_load_lds(16B) staging into
//    unpadded LDS with XOR k-chunk swizzle (conflict-free ds_read_b128).
// ---------------------------------------------------------------------------
template <bool GATHER, bool RELU2, bool OUTF32>
__global__ __launch_bounds__(256, 2) void gemm_kernel(
    const unsigned short* __restrict__ A, const unsigned short* __restrict__ B,
    void* __restrict__ Cout,
    const int* __restrict__ cnt, const int* __restrict__ basep,
    const int* __restrict__ tlist,
    int N, int K, int fixedM) {
    const int e = blockIdx.z;
    const int M = cnt ? min(cnt[e], CAP) : fixedM;
    const int m0 = blockIdx.y * 128;
    if (m0 >= M) return;
    const int n0 = blockIdx.x * 128;
    const int rowbase = basep ? basep[e] : 0;
    const unsigned short* Be = B + (size_t)e * (size_t)N * K;

    __shared__ __align__(16) unsigned short a_s[128 * 64];
    __shared__ __align__(16) unsigned short b_s[128 * 64];

    const int tid  = threadIdx.x;
    const int w    = tid >> 6;
    const int lane = tid & 63;
    const int rsub = lane >> 3;             // 0..7 row within 8-row chunk
    const int csw  = (lane & 7) ^ rsub;     // swizzled k-chunk this lane fetches

    const unsigned short* aptr[4];
    const unsigned short* bptr[4];
#pragma unroll
    for (int j = 0; j < 4; j++) {
        int r = m0 + w * 32 + j * 8 + rsub;
        if (GATHER) {
            int t = (r < M) ? tlist[e * CAP + r] : 0;
            aptr[j] = A + (size_t)t * K + csw * 8;
        } else {
            int rr = (r < M) ? r : (M - 1);
            aptr[j] = A + (size_t)(rowbase + rr) * K + csw * 8;
        }
        bptr[j] = Be + (size_t)(n0 + w * 32 + j * 8 + rsub) * K + csw * 8;
    }

    const int wm = (w >> 1) * 64, wn = (w & 1) * 64;
    const int lm = lane & 15, q = lane >> 4;
    const int swm = lm & 7;

    floatx4 acc[4][4];
#pragma unroll
    for (int a = 0; a < 4; a++)
#pragma unroll
        for (int b2 = 0; b2 < 4; b2++) acc[a][b2] = (floatx4){0.f, 0.f, 0.f, 0.f};

    for (int k0 = 0; k0 < K; k0 += 64) {
#pragma unroll
        for (int j = 0; j < 4; j++) {
            gload_lds16(aptr[j] + k0, &a_s[(w * 32 + j * 8) * 64]);
            gload_lds16(bptr[j] + k0, &b_s[(w * 32 + j * 8) * 64]);
        }
        __syncthreads();
#pragma unroll
        for (int kk = 0; kk < 2; kk++) {
            short8 af[4], bfr[4];
            const int ca = ((kk * 4 + q) ^ swm) * 8;
#pragma unroll
            for (int i = 0; i < 4; i++) {
                af[i]  = *(const short8*)&a_s[(wm + i * 16 + lm) * 64 + ca];
                bfr[i] = *(const short8*)&b_s[(wn + i * 16 + lm) * 64 + ca];
            }
#pragma unroll
            for (int mi = 0; mi < 4; mi++)
#pragma unroll
                for (int ni = 0; ni < 4; ni++)
                    acc[mi][ni] = __builtin_amdgcn_mfma_f32_16x16x32_bf16(
                        af[mi], bfr[ni], acc[mi][ni], 0, 0, 0);
        }
        __syncthreads();
    }

#pragma unroll
    for (int mi = 0; mi < 4; mi++) {
#pragma unroll
        for (int i = 0; i < 4; i++) {
            int r = wm + mi * 16 + q * 4 + i;
            if (m0 + r < M) {
                size_t Rrow = (size_t)(rowbase + m0 + r);
#pragma unroll
                for (int ni = 0; ni < 4; ni++) {
                    float v = acc[mi][ni][i];
                    if (RELU2) { v = v > 0.f ? v * v : 0.f; }
                    int c = n0 + wn + ni * 16 + lm;
                    if (OUTF32) ((float*)Cout)[Rrow * N + c] = v;
                    else        ((unsigned short*)Cout)[Rrow * N + c] = f2bf(v);
                }
            }
        }
    }
}

// ---------------------------------------------------------------------------
// 7) Combine: out[t] += SCALE * sum_k w[t,k] * Y[base[id]+pos]
// ---------------------------------------------------------------------------
__global__ __launch_bounds__(256) void combine_kernel(
    const unsigned short* __restrict__ Y, const int* __restrict__ ids,
    const float* __restrict__ wts, const int* __restrict__ poss,
    const int* __restrict__ base, float* __restrict__ out) {
    __shared__ int   s_slot[K_TOP];
    __shared__ float s_w[K_TOP];
    const int t = blockIdx.x, tid = threadIdx.x;
    if (tid < K_TOP) {
        int id = ids[(size_t)t * K_TOP + tid];
        int p  = poss[(size_t)t * K_TOP + tid];
        s_slot[tid] = (p >= 0) ? (base[id] + p) : -1;
        s_w[tid]    = wts[(size_t)t * K_TOP + tid];
    }
    __syncthreads();
    const int c = tid * 4;
    float a0 = 0.f, a1 = 0.f, a2 = 0.f, a3 = 0.f;
#pragma unroll
    for (int k = 0; k < K_TOP; k++) {
        int slot = s_slot[k];
        if (slot >= 0) {
            float wkk = s_w[k];
            ushort4 y = *(const ushort4*)(Y + (size_t)slot * H_DIM + c);
            a0 += wkk * bf2f(y.x); a1 += wkk * bf2f(y.y);
            a2 += wkk * bf2f(y.z); a3 += wkk * bf2f(y.w);
        }
    }
    float4 o = *(float4*)(out + (size_t)t * H_DIM + c);
    o.x += SCALE * a0; o.y += SCALE * a1; o.z += SCALE * a2; o.w += SCALE * a3;
    *(float4*)(out + (size_t)t * H_DIM + c) = o;
}

// ---------------------------------------------------------------------------
extern "C" void kernel_launch(void* const* d_in, const int* in_sizes, int n_in,
                              void* d_out, int out_size, void* d_ws, size_t ws_size,
                              hipStream_t stream) {
    const float* x         = (const float*)d_in[0];
    const float* gate_w    = (const float*)d_in[1];
    const float* gate_bias = (const float*)d_in[2];
    const float* w_up      = (const float*)d_in[3];
    const float* w_down    = (const float*)d_in[4];
    const float* sh_up     = (const float*)d_in[5];
    const float* sh_down   = (const float*)d_in[6];
    float* out = (float*)d_out;

    char* ws = (char*)d_ws;
    size_t off = 0;
    auto alloc = [&](size_t b) { size_t o = off; off += (b + 255) & ~(size_t)255; return o; };
    float*          logits = (float*)(ws + alloc((size_t)T_DIM * E_NUM * 4));
    float*          part   = (float*)(ws + alloc((size_t)4 * T_DIM * E_NUM * 4));
    int*            ids    = (int*)  (ws + alloc((size_t)T_DIM * K_TOP * 4));
    float*          wts    = (float*)(ws + alloc((size_t)T_DIM * K_TOP * 4));
    int*            poss   = (int*)  (ws + alloc((size_t)T_DIM * K_TOP * 4));
    int*            cnt    = (int*)  (ws + alloc(256));
    int*            base   = (int*)  (ws + alloc(256));
    int*            tlist  = (int*)  (ws + alloc((size_t)E_NUM * CAP * 4));
    unsigned short* xb     = (unsigned short*)(ws + alloc((size_t)T_DIM * H_DIM * 2));
    unsigned short* wupT   = (unsigned short*)(ws + alloc((size_t)E_NUM * H_DIM * I_DIM * 2));
    unsigned short* wdnT   = (unsigned short*)(ws + alloc((size_t)E_NUM * H_DIM * I_DIM * 2));
    unsigned short* shupT  = (unsigned short*)(ws + alloc((size_t)H_DIM * H_DIM * 2));
    unsigned short* shdnT  = (unsigned short*)(ws + alloc((size_t)H_DIM * H_DIM * 2));
    unsigned short* hact   = (unsigned short*)(ws + alloc((size_t)T_DIM * K_TOP * I_DIM * 2));
    unsigned short* Ybuf   = (unsigned short*)(ws + alloc((size_t)T_DIM * K_TOP * H_DIM * 2));
    unsigned short* smid   = (unsigned short*)(ws + alloc((size_t)T_DIM * H_DIM * 2));

    hipMemsetAsync(cnt, 0, 256, stream);

    router_partial_kernel<<<dim3(T_DIM / 64, 4), 256, 0, stream>>>(x, gate_w, part);
    router_reduce_kernel<<<dim3((T_DIM * E_NUM / 4) / 256), 256, 0, stream>>>(part, logits);
    route_kernel<<<dim3(T_DIM / 64), 64, 0, stream>>>(logits, gate_bias, ids, wts, poss, cnt, tlist);
    scan_kernel<<<1, 64, 0, stream>>>(cnt, base);
    cvt_x_kernel<<<dim3((T_DIM * H_DIM / 4) / 256), 256, 0, stream>>>(x, xb);
    transpose_kernel<<<dim3(I_DIM / 64, H_DIM / 64, E_NUM), 256, 0, stream>>>(w_up, wupT, H_DIM, I_DIM);
    transpose_kernel<<<dim3(H_DIM / 64, I_DIM / 64, E_NUM), 256, 0, stream>>>(w_down, wdnT, I_DIM, H_DIM);
    transpose_kernel<<<dim3(H_DIM / 64, H_DIM / 64, 1), 256, 0, stream>>>(sh_up, shupT, H_DIM, H_DIM);
    transpose_kernel<<<dim3(H_DIM / 64, H_DIM / 64, 1), 256, 0, stream>>>(sh_down, shdnT, H_DIM, H_DIM);

    gemm_kernel<true, true, false><<<dim3(I_DIM / 128, CAP / 128, E_NUM), 256, 0, stream>>>(
        xb, wupT, hact, cnt, base, tlist, I_DIM, H_DIM, 0);
    gemm_kernel<false, false, false><<<dim3(H_DIM / 128, CAP / 128, E_NUM), 256, 0, stream>>>(
        hact, wdnT, Ybuf, cnt, base, nullptr, H_DIM, I_DIM, 0);
    gemm_kernel<false, true, false><<<dim3(H_DIM / 128, T_DIM / 128, 1), 256, 0, stream>>>(
        xb, shupT, smid, nullptr, nullptr, nullptr, H_DIM, H_DIM, T_DIM);
    gemm_kernel<false, false, true><<<dim3(H_DIM / 128, T_DIM / 128, 1), 256, 0, stream>>>(
        smid, shdnT, out, nullptr, nullptr, nullptr, H_DIM, H_DIM, T_DIM);
    combine_kernel<<<dim3(T_DIM), 256, 0, stream>>>(Ybuf, ids, wts, poss, base, out);
    (void)in_sizes; (void)n_in; (void)out_size; (void)ws_size;
}